// Round 2
// baseline (228.668 us; speedup 1.0000x reference)
//
#include <hip/hip_runtime.h>
#include <utility>
#include <cstddef>

#define NCOLS  985        // 1 + 16 + 136 + 816 + 16
#define CHUNK  62         // 15*62 + 55 = 985
#define NCHUNK 16
#define PITCH  63         // slab col pitch (odd -> bank-conflict-free writes)

// ---- compile-time combinatorial decoders (match itertools order) ----
constexpr int pair_i_f(int p){ int i=0; while (p >= 16-i){ p -= 16-i; ++i; } return i; }
constexpr int pair_j_f(int p){ int i=0; while (p >= 16-i){ p -= 16-i; ++i; } return i+p; }
constexpr int tcount(int i){ return (16-i)*(17-i)/2; }
constexpr int trip_i_f(int t){ int i=0; while (t >= tcount(i)){ t -= tcount(i); ++i; } return i; }
constexpr int trip_j_f(int t){ int i=0; while (t >= tcount(i)){ t -= tcount(i); ++i; }
                               int j=i; while (t >= 16-j){ t -= 16-j; ++j; } return j; }
constexpr int trip_k_f(int t){ int i=0; while (t >= tcount(i)){ t -= tcount(i); ++i; }
                               int j=i; while (t >= 16-j){ t -= 16-j; ++j; } return j+t; }

// ---- one output column, fully static indices -> zc stays in VGPRs ----
template<int E>
__device__ __forceinline__ float term(const float (&zc)[16]) {
  if constexpr (E == 0) {
    return 1.0f;
  } else if constexpr (E <= 16) {
    return zc[E-1];
  } else if constexpr (E < 17 + 136) {
    constexpr int p = E - 17;
    constexpr int i = pair_i_f(p), j = pair_j_f(p);
    return zc[i] * zc[j];
  } else if constexpr (E < 17 + 136 + 816) {
    constexpr int t = E - 153;
    constexpr int i = trip_i_f(t), j = trip_j_f(t), k = trip_k_f(t);
    return (zc[i] * zc[j]) * zc[k];   // (zi*zj) CSE'd across the k-run
  } else {
    return __sinf(zc[E - 969]);
  }
}

template<int BEG, int... Is>
__device__ __forceinline__ void chunk_compute(const float (&zc)[16], float* sl,
                                              std::integer_sequence<int, Is...>) {
  ((sl[Is] = term<BEG + Is>(zc)), ...);   // ds_write_b32 with imm offsets
}

template<int C>
__device__ __forceinline__ void do_chunk(const float (&zc)[16], float* sl, float* slw,
                                         float* outbase, int lane, int nrows) {
  constexpr int BEG = C * CHUNK;
  constexpr int LEN = (BEG + CHUNK <= NCOLS) ? CHUNK : (NCOLS - BEG);
  // compute: lane = row, static cols [BEG, BEG+LEN)
  chunk_compute<BEG>(zc, sl, std::make_integer_sequence<int, LEN>{});
  __builtin_amdgcn_sched_barrier(0);   // pin write->read order (per-wave slab, DS in-order)
  // transpose out of LDS: lane = column, loop rows; coalesced 4B-aligned stores
  float* op = outbase + BEG + lane;
  #pragma unroll 8
  for (int rr = 0; rr < 64; ++rr) {
    float v = slw[rr * PITCH + lane];
    if (lane < LEN && rr < nrows) op[(size_t)rr * NCOLS] = v;
  }
  __builtin_amdgcn_sched_barrier(0);   // pin read->next-chunk-write order
}

template<int... Cs>
__device__ __forceinline__ void all_chunks(const float (&zc)[16], float* sl, float* slw,
                                           float* outbase, int lane, int nrows,
                                           std::integer_sequence<int, Cs...>) {
  (do_chunk<Cs>(zc, sl, slw, outbase, lane, nrows), ...);
}

__global__ __launch_bounds__(256) void sindy_kernel(const float* __restrict__ z,
                                                    const float* __restrict__ dz,
                                                    float* __restrict__ out, int batch) {
  __shared__ float slab[4][64 * PITCH];   // 64512 B, one slab per wave

  const int w    = threadIdx.x >> 6;
  const int lane = threadIdx.x & 63;
  const int row0 = blockIdx.x * 256 + w * 64;   // this wave's first row
  if (row0 >= batch) return;                     // no barriers -> safe early exit
  const int nrows = (batch - row0 < 64) ? (batch - row0) : 64;

  // load this lane's row (16 zc values) into registers
  const int lrow = (row0 + lane < batch) ? (row0 + lane) : (batch - 1);
  float zc[16];
  {
    const float4* zp = (const float4*)(z  + (size_t)lrow * 8);
    const float4* dp = (const float4*)(dz + (size_t)lrow * 8);
    float4 a = zp[0], b = zp[1], c = dp[0], d = dp[1];
    zc[0]=a.x;  zc[1]=a.y;  zc[2]=a.z;  zc[3]=a.w;
    zc[4]=b.x;  zc[5]=b.y;  zc[6]=b.z;  zc[7]=b.w;
    zc[8]=c.x;  zc[9]=c.y;  zc[10]=c.z; zc[11]=c.w;
    zc[12]=d.x; zc[13]=d.y; zc[14]=d.z; zc[15]=d.w;
  }

  float* slw = slab[w];
  float* sl  = slw + lane * PITCH;
  float* outbase = out + (size_t)row0 * NCOLS;

  all_chunks(zc, sl, slw, outbase, lane, nrows,
             std::make_integer_sequence<int, NCHUNK>{});
}

extern "C" void kernel_launch(void* const* d_in, const int* in_sizes, int n_in,
                              void* d_out, int out_size, void* d_ws, size_t ws_size,
                              hipStream_t stream) {
  const float* z  = (const float*)d_in[0];
  const float* dz = (const float*)d_in[1];
  float* out = (float*)d_out;
  const int batch = in_sizes[0] / 8;   // LATENT_DIM = 8

  const int blocks = (batch + 255) / 256;   // 256 rows per block (4 waves x 64)
  sindy_kernel<<<blocks, 256, 0, stream>>>(z, dz, out, batch);
}